// Round 3
// baseline (203.508 us; speedup 1.0000x reference)
//
#include <hip/hip_runtime.h>
#include <math.h>

#define N_NODES 50000
#define N_EDGES 640000
#define DIM 128
#define EDGE_DIM 16
#define N_HEADS 4
#define HEAD_DIM 32
#define CAPB 48   // bucket capacity; Poisson(12.8) P(deg>=48)*50K ~ 1e-9

typedef __attribute__((ext_vector_type(8))) short bf16x8;
typedef __attribute__((ext_vector_type(4))) float floatx4;

__device__ __forceinline__ unsigned short f2bf(float f) {
    unsigned int x = __float_as_uint(f);
    return (unsigned short)((x + 0x7FFFu + ((x >> 16) & 1u)) >> 16);
}
__device__ __forceinline__ float bf2f(unsigned short u) {
    return __uint_as_float(((unsigned int)u) << 16);
}
__device__ __forceinline__ float bfu2f_lo(unsigned int u) {
    return __uint_as_float(u << 16);
}
__device__ __forceinline__ float bfu2f_hi(unsigned int u) {
    return __uint_as_float(u & 0xFFFF0000u);
}

// ---------------------------------------------------------------- GEMM (all-in-one)
// Per block: stage W->LDS (bf16, chunk-major), compute P in-block, zero counts
// slice, then 4 waves x 16 nodes of MFMA (W-fragments via ds_read_b128).
__global__ __launch_bounds__(256) void k_gemm(
    const float* __restrict__ h,     // [N,128] fp32
    const float* __restrict__ W,     // [128,128] fp32
    const float* __restrict__ a,     // [4,64] fp32
    unsigned short* __restrict__ Whbf,  // [N,128] bf16
    float* __restrict__ sc,          // [N,8]: 4 ssrc then 4 sdst
    int* __restrict__ counts)
{
    __shared__ unsigned short w_lds[16 * 128 * 8];  // 32 KB
    __shared__ unsigned short p_lds[16 * 16 * 8];   // 4 KB
    int t = threadIdx.x;

    if (t < 64) {                                   // zero counts slice
        int ci = blockIdx.x * 64 + t;
        if (ci < N_NODES) counts[ci] = 0;
    }

    // stage W: thread t handles row r = t>>1, col half (t&1)*64 .. +63
    {
        int r = t >> 1, halfc = t & 1;
        const float* wr = W + (size_t)r * DIM + halfc * 64;
#pragma unroll
        for (int j = 0; j < 8; ++j) {
            float4 x0 = *(const float4*)(wr + j * 8);
            float4 x1 = *(const float4*)(wr + j * 8 + 4);
            bf16x8 f;
            f[0] = (short)f2bf(x0.x); f[1] = (short)f2bf(x0.y);
            f[2] = (short)f2bf(x0.z); f[3] = (short)f2bf(x0.w);
            f[4] = (short)f2bf(x1.x); f[5] = (short)f2bf(x1.y);
            f[6] = (short)f2bf(x1.z); f[7] = (short)f2bf(x1.w);
            int ch = halfc * 8 + j;
            *(bf16x8*)&w_lds[(ch * 128 + r) * 8] = f;
        }
    }
    // zero P pad rows 8..15
    {
        unsigned int* p32 = (unsigned int*)p_lds;
        int ch = t >> 4, sub = t & 15;
        p32[ch * 64 + 32 + sub] = 0;
        p32[ch * 64 + 48 + sub] = 0;
    }
    __syncthreads();

    // P[j][c] = sum_d W[hh*32+d][c] * a[hh*64+off+d]   (j<4: src, j>=4: dst)
    if (t < 128) {
        int j = t & 7, cg = t >> 3;        // cg = column group (8 cols), 0..15
        int hh = j & 3, off = (j >> 2) * 32;
        int rot = t & 7;                   // d-rotation caps LDS conflicts
        float dot[8] = {0.f, 0.f, 0.f, 0.f, 0.f, 0.f, 0.f, 0.f};
        for (int dd = 0; dd < 32; ++dd) {
            int d = (dd + rot) & 31;
            bf16x8 wv = *(const bf16x8*)&w_lds[(cg * 128 + hh * 32 + d) * 8];
            float av = a[hh * 64 + off + d];
#pragma unroll
            for (int k = 0; k < 8; ++k)
                dot[k] += bf2f((unsigned short)wv[k]) * av;
        }
        bf16x8 pf;
#pragma unroll
        for (int k = 0; k < 8; ++k) pf[k] = (short)f2bf(dot[k]);
        *(bf16x8*)&p_lds[(cg * 16 + j) * 8] = pf;
    }
    __syncthreads();

    // MFMA gemm: wave handles 16 nodes; D = mfma(A=W/P rows, B=h rows)
    int wave = t >> 6, lane = t & 63;
    int nb = blockIdx.x * 64 + wave * 16;
    int m = lane & 15, q = lane >> 4;
    int node = nb + m;
    bool nvalid = node < N_NODES;

    bf16x8 hfrag[4];
#pragma unroll
    for (int kt = 0; kt < 4; ++kt) {
        bf16x8 f;
        if (nvalid) {
            const float* p = h + (size_t)node * DIM + kt * 32 + q * 8;
            float4 x0 = *(const float4*)(p);
            float4 x1 = *(const float4*)(p + 4);
            f[0] = (short)f2bf(x0.x); f[1] = (short)f2bf(x0.y);
            f[2] = (short)f2bf(x0.z); f[3] = (short)f2bf(x0.w);
            f[4] = (short)f2bf(x1.x); f[5] = (short)f2bf(x1.y);
            f[6] = (short)f2bf(x1.z); f[7] = (short)f2bf(x1.w);
        } else {
#pragma unroll
            for (int j = 0; j < 8; ++j) f[j] = 0;
        }
        hfrag[kt] = f;
    }

    // scores tile: D rows 0..7 = {ssrc[4], sdst[4]}, cols = nodes
    floatx4 accS = {0.f, 0.f, 0.f, 0.f};
#pragma unroll
    for (int kt = 0; kt < 4; ++kt) {
        bf16x8 pfrag = *(const bf16x8*)&p_lds[((kt * 4 + q) * 16 + m) * 8];
        accS = __builtin_amdgcn_mfma_f32_16x16x32_bf16(pfrag, hfrag[kt], accS, 0, 0, 0);
    }
    if (q < 2 && nvalid) {
        *(float4*)(sc + (size_t)node * 8 + q * 4) =
            make_float4(accS[0], accS[1], accS[2], accS[3]);
    }

#pragma unroll
    for (int dt = 0; dt < 8; ++dt) {
        floatx4 acc = {0.f, 0.f, 0.f, 0.f};
#pragma unroll
        for (int kt = 0; kt < 4; ++kt) {
            bf16x8 wfrag = *(const bf16x8*)&w_lds[((kt * 4 + q) * 128 + dt * 16 + m) * 8];
            acc = __builtin_amdgcn_mfma_f32_16x16x32_bf16(wfrag, hfrag[kt], acc, 0, 0, 0);
        }
        // lane(m,q) holds Wh[node m][dt*16 + q*4 + r] -> packed 8B store
        if (nvalid) {
            unsigned int lo = ((unsigned int)f2bf(acc[1]) << 16) | f2bf(acc[0]);
            unsigned int hi = ((unsigned int)f2bf(acc[3]) << 16) | f2bf(acc[2]);
            uint2 pk; pk.x = lo; pk.y = hi;
            *(uint2*)(Whbf + (size_t)node * DIM + dt * 16 + q * 4) = pk;
        }
    }
}

// ---------------------------------------------------------------- edge logits -> exp -> packed record
// No LDS, no barrier: each edge's ef row is exactly one 64B line, so the
// thread loads its own row (4x float4 from the same line; first load fetches
// the line, rest hit L1). We[4][16] is lane-uniform -> s_load. All global
// loads + the atomic are issued up front; VALU tail overlaps their latency.
__global__ __launch_bounds__(256) void k_scatter(
    const int* __restrict__ ei,
    const float* __restrict__ ef,   // [E,16]
    const float* __restrict__ We,   // [4,16]
    const float* __restrict__ sc,   // [N,8]
    int* __restrict__ counts,
    uint4* __restrict__ brec)
{
    int e = blockIdx.x * 256 + threadIdx.x;   // grid exact: E/256 blocks

    // own-row ef load (one cache line)
    const float4* fr = (const float4*)(ef + (size_t)e * 16);
    float4 f0 = fr[0], f1 = fr[1], f2 = fr[2], f3 = fr[3];

    // edge indices, bucket slot, score gathers — all independent, in flight
    int src = ei[e], dst = ei[N_EDGES + e];
    int slot = atomicAdd(counts + dst, 1);
    float4 ss = *(const float4*)(sc + (size_t)src * 8);
    float4 sd = *(const float4*)(sc + (size_t)dst * 8 + 4);

    float lg[4] = {ss.x + sd.x, ss.y + sd.y, ss.z + sd.z, ss.w + sd.w};
#pragma unroll
    for (int hh = 0; hh < 4; ++hh) {
        const float4* wep = (const float4*)(We + hh * 16);
        float4 w0 = wep[0], w1 = wep[1], w2 = wep[2], w3 = wep[3];
        float ed = f0.x * w0.x + f0.y * w0.y + f0.z * w0.z + f0.w * w0.w
                 + f1.x * w1.x + f1.y * w1.y + f1.z * w1.z + f1.w * w1.w
                 + f2.x * w2.x + f2.y * w2.y + f2.z * w2.z + f2.w * w2.w
                 + f3.x * w3.x + f3.y * w3.y + f3.z * w3.z + f3.w * w3.w;
        float s = lg[hh];
        s = s > 0.f ? s : 0.2f * s;   // leaky_relu(0.2) on node-score part only
        lg[hh] = __expf(s + ed);      // softmax numerator (no max-sub; |s| bounded)
    }
    if (slot < CAPB) {
        uint4 rec;
        rec.x = (unsigned int)src;
        rec.y = ((unsigned int)f2bf(lg[1]) << 16) | f2bf(lg[0]);
        rec.z = ((unsigned int)f2bf(lg[3]) << 16) | f2bf(lg[2]);
        rec.w = 0;
        brec[(size_t)dst * CAPB + slot] = rec;
    }
}

// ---------------------------------------------------------------- fused agg + GELU + LN
// one wave per node; half-wave owns all 128 dims (4 dims/lane, 8B loads),
// two edges per j-step -> 8 cache lines in flight per load instruction.
__global__ __launch_bounds__(256) void k_node(
    const int* __restrict__ counts,
    const uint4* __restrict__ brec,
    const unsigned short* __restrict__ Whbf,
    const float* __restrict__ ln_scale, const float* __restrict__ ln_bias,
    float* __restrict__ out)
{
    __shared__ __align__(16) float p_s[4][CAPB * 4];
    __shared__ int s_s[4][CAPB];
    int w = threadIdx.x >> 6, l = threadIdx.x & 63;
    int n = blockIdx.x * 4 + w;                    // grid exact: 12500 blocks
    int deg = counts[n];
    deg = deg < CAPB ? deg : CAPB;
    size_t base = (size_t)n * CAPB;

    if (l < CAPB) {
        uint4 rec = make_uint4(0u, 0u, 0u, 0u);
        if (l < deg) rec = brec[base + l];
        float4 pv;
        pv.x = bfu2f_lo(rec.y); pv.y = bfu2f_hi(rec.y);
        pv.z = bfu2f_lo(rec.z); pv.w = bfu2f_hi(rec.z);
        *(float4*)&p_s[w][l * 4] = pv;             // zero-padded to CAPB
        s_s[w][l] = (int)rec.x;                    // pad src=0 (p=0 kills it)
    }
    __syncthreads();

    int li = l & 31, half = l >> 5;
    int hb = li >> 3;                              // head of dims li*4..+3
    float den = 0.f, b0 = 0.f, b1 = 0.f, b2 = 0.f, b3 = 0.f;
    int nch = (deg + 15) >> 4;                     // 16 edges per chunk (2/j-step)
    for (int c = 0; c < nch; ++c) {
        int e0 = c * 16 + half;
        float pv[8];
        uint2 uu[8];
#pragma unroll
        for (int j = 0; j < 8; ++j) {
            int e = e0 + j * 2;                    // e <= 47 < CAPB (zero-padded)
            int src = s_s[w][e];
            pv[j] = p_s[w][e * 4 + hb];
            uu[j] = *(const uint2*)(Whbf + (size_t)src * DIM + li * 4);
        }
#pragma unroll
        for (int j = 0; j < 8; ++j) {
            den += pv[j];
            b0 += pv[j] * bfu2f_lo(uu[j].x);
            b1 += pv[j] * bfu2f_hi(uu[j].x);
            b2 += pv[j] * bfu2f_lo(uu[j].y);
            b3 += pv[j] * bfu2f_hi(uu[j].y);
        }
    }
    // combine the two half-wave edge partitions (same dims in lanes l, l^32)
    den += __shfl_xor(den, 32, 64);
    b0 += __shfl_xor(b0, 32, 64);
    b1 += __shfl_xor(b1, 32, 64);
    b2 += __shfl_xor(b2, 32, 64);
    b3 += __shfl_xor(b3, 32, 64);

    float dd = den + 1e-9f;
    float x0 = b0 / dd, x1 = b1 / dd, x2 = b2 / dd, x3 = b3 / dd;
    const float k = 0.70710678118654752f;
    float g0 = 0.5f * x0 * (1.f + erff(x0 * k));
    float g1 = 0.5f * x1 * (1.f + erff(x1 * k));
    float g2 = 0.5f * x2 * (1.f + erff(x2 * k));
    float g3 = 0.5f * x3 * (1.f + erff(x3 * k));
    float s = g0 + g1 + g2 + g3;
    float ss = g0 * g0 + g1 * g1 + g2 * g2 + g3 * g3;
#pragma unroll
    for (int off = 1; off <= 16; off <<= 1) {      // reduce within 32-lane half
        s += __shfl_xor(s, off, 64);
        ss += __shfl_xor(ss, off, 64);
    }
    float mu = s * (1.f / 128.f);
    float var = ss * (1.f / 128.f) - mu * mu;
    float rstd = rsqrtf(var + 1e-5f);
    if (half == 0) {
        float4 sca = *(const float4*)(ln_scale + li * 4);
        float4 bi = *(const float4*)(ln_bias + li * 4);
        float4 o;
        o.x = (g0 - mu) * rstd * sca.x + bi.x;
        o.y = (g1 - mu) * rstd * sca.y + bi.y;
        o.z = (g2 - mu) * rstd * sca.z + bi.z;
        o.w = (g3 - mu) * rstd * sca.w + bi.w;
        *(float4*)(out + (size_t)n * DIM + li * 4) = o;
    }
}

extern "C" void kernel_launch(void* const* d_in, const int* in_sizes, int n_in,
                              void* d_out, int out_size, void* d_ws, size_t ws_size,
                              hipStream_t stream) {
    const float* h   = (const float*)d_in[0];
    const int*   ei  = (const int*)d_in[1];
    const float* ef  = (const float*)d_in[2];
    const float* W   = (const float*)d_in[3];
    const float* We  = (const float*)d_in[4];
    const float* a   = (const float*)d_in[5];
    const float* lsc = (const float*)d_in[6];
    const float* lbi = (const float*)d_in[7];

    char* ws = (char*)d_ws;
    size_t off = 0;
    unsigned short* Whbf = (unsigned short*)(ws + off); off += (size_t)N_NODES * DIM * 2;
    float* sc    = (float*)(ws + off); off += (size_t)N_NODES * 8 * 4;
    int*   counts= (int*)(ws + off);   off += (size_t)N_NODES * 4;
    uint4* brec  = (uint4*)(ws + off); off += (size_t)N_NODES * CAPB * 16;

    k_gemm<<<(N_NODES + 63) / 64, 256, 0, stream>>>(h, W, a, Whbf, sc, counts);
    k_scatter<<<N_EDGES / 256, 256, 0, stream>>>(ei, ef, We, sc, counts, brec);
    k_node<<<N_NODES / 4, 256, 0, stream>>>(counts, brec, Whbf, lsc, lbi,
                                            (float*)d_out);
}

// Round 4
// 195.833 us; speedup vs baseline: 1.0392x; 1.0392x over previous
//
#include <hip/hip_runtime.h>
#include <math.h>

#define N_NODES 50000
#define N_EDGES 640000
#define DIM 128
#define EDGE_DIM 16
#define N_HEADS 4
#define HEAD_DIM 32
#define CAPB 48   // bucket capacity; Poisson(12.8) P(deg>=48)*50K ~ 1e-9

typedef __attribute__((ext_vector_type(8))) short bf16x8;
typedef __attribute__((ext_vector_type(4))) float floatx4;

__device__ __forceinline__ unsigned short f2bf(float f) {
    unsigned int x = __float_as_uint(f);
    return (unsigned short)((x + 0x7FFFu + ((x >> 16) & 1u)) >> 16);
}
__device__ __forceinline__ float bf2f(unsigned short u) {
    return __uint_as_float(((unsigned int)u) << 16);
}
__device__ __forceinline__ float bfu2f_lo(unsigned int u) {
    return __uint_as_float(u << 16);
}
__device__ __forceinline__ float bfu2f_hi(unsigned int u) {
    return __uint_as_float(u & 0xFFFF0000u);
}

// ---------------------------------------------------------------- GEMM (all-in-one)
// Per block: stage W->LDS (bf16, chunk-major), compute P in-block, zero counts
// slice, then 4 waves x 16 nodes of MFMA (W-fragments via ds_read_b128).
__global__ __launch_bounds__(256) void k_gemm(
    const float* __restrict__ h,     // [N,128] fp32
    const float* __restrict__ W,     // [128,128] fp32
    const float* __restrict__ a,     // [4,64] fp32
    unsigned short* __restrict__ Whbf,  // [N,128] bf16
    float* __restrict__ sc,          // [N,8]: 4 ssrc then 4 sdst
    int* __restrict__ counts)
{
    __shared__ unsigned short w_lds[16 * 128 * 8];  // 32 KB
    __shared__ unsigned short p_lds[16 * 16 * 8];   // 4 KB
    int t = threadIdx.x;

    if (t < 64) {                                   // zero counts slice
        int ci = blockIdx.x * 64 + t;
        if (ci < N_NODES) counts[ci] = 0;
    }

    // stage W: thread t handles row r = t>>1, col half (t&1)*64 .. +63
    {
        int r = t >> 1, halfc = t & 1;
        const float* wr = W + (size_t)r * DIM + halfc * 64;
#pragma unroll
        for (int j = 0; j < 8; ++j) {
            float4 x0 = *(const float4*)(wr + j * 8);
            float4 x1 = *(const float4*)(wr + j * 8 + 4);
            bf16x8 f;
            f[0] = (short)f2bf(x0.x); f[1] = (short)f2bf(x0.y);
            f[2] = (short)f2bf(x0.z); f[3] = (short)f2bf(x0.w);
            f[4] = (short)f2bf(x1.x); f[5] = (short)f2bf(x1.y);
            f[6] = (short)f2bf(x1.z); f[7] = (short)f2bf(x1.w);
            int ch = halfc * 8 + j;
            *(bf16x8*)&w_lds[(ch * 128 + r) * 8] = f;
        }
    }
    // zero P pad rows 8..15
    {
        unsigned int* p32 = (unsigned int*)p_lds;
        int ch = t >> 4, sub = t & 15;
        p32[ch * 64 + 32 + sub] = 0;
        p32[ch * 64 + 48 + sub] = 0;
    }
    __syncthreads();

    // P[j][c] = sum_d W[hh*32+d][c] * a[hh*64+off+d]   (j<4: src, j>=4: dst)
    if (t < 128) {
        int j = t & 7, cg = t >> 3;        // cg = column group (8 cols), 0..15
        int hh = j & 3, off = (j >> 2) * 32;
        int rot = t & 7;                   // d-rotation caps LDS conflicts
        float dot[8] = {0.f, 0.f, 0.f, 0.f, 0.f, 0.f, 0.f, 0.f};
        for (int dd = 0; dd < 32; ++dd) {
            int d = (dd + rot) & 31;
            bf16x8 wv = *(const bf16x8*)&w_lds[(cg * 128 + hh * 32 + d) * 8];
            float av = a[hh * 64 + off + d];
#pragma unroll
            for (int k = 0; k < 8; ++k)
                dot[k] += bf2f((unsigned short)wv[k]) * av;
        }
        bf16x8 pf;
#pragma unroll
        for (int k = 0; k < 8; ++k) pf[k] = (short)f2bf(dot[k]);
        *(bf16x8*)&p_lds[(cg * 16 + j) * 8] = pf;
    }
    __syncthreads();

    // MFMA gemm: wave handles 16 nodes; D = mfma(A=W/P rows, B=h rows)
    int wave = t >> 6, lane = t & 63;
    int nb = blockIdx.x * 64 + wave * 16;
    int m = lane & 15, q = lane >> 4;
    int node = nb + m;
    bool nvalid = node < N_NODES;

    bf16x8 hfrag[4];
#pragma unroll
    for (int kt = 0; kt < 4; ++kt) {
        bf16x8 f;
        if (nvalid) {
            const float* p = h + (size_t)node * DIM + kt * 32 + q * 8;
            float4 x0 = *(const float4*)(p);
            float4 x1 = *(const float4*)(p + 4);
            f[0] = (short)f2bf(x0.x); f[1] = (short)f2bf(x0.y);
            f[2] = (short)f2bf(x0.z); f[3] = (short)f2bf(x0.w);
            f[4] = (short)f2bf(x1.x); f[5] = (short)f2bf(x1.y);
            f[6] = (short)f2bf(x1.z); f[7] = (short)f2bf(x1.w);
        } else {
#pragma unroll
            for (int j = 0; j < 8; ++j) f[j] = 0;
        }
        hfrag[kt] = f;
    }

    // scores tile: D rows 0..7 = {ssrc[4], sdst[4]}, cols = nodes
    floatx4 accS = {0.f, 0.f, 0.f, 0.f};
#pragma unroll
    for (int kt = 0; kt < 4; ++kt) {
        bf16x8 pfrag = *(const bf16x8*)&p_lds[((kt * 4 + q) * 16 + m) * 8];
        accS = __builtin_amdgcn_mfma_f32_16x16x32_bf16(pfrag, hfrag[kt], accS, 0, 0, 0);
    }
    if (q < 2 && nvalid) {
        *(float4*)(sc + (size_t)node * 8 + q * 4) =
            make_float4(accS[0], accS[1], accS[2], accS[3]);
    }

#pragma unroll
    for (int dt = 0; dt < 8; ++dt) {
        floatx4 acc = {0.f, 0.f, 0.f, 0.f};
#pragma unroll
        for (int kt = 0; kt < 4; ++kt) {
            bf16x8 wfrag = *(const bf16x8*)&w_lds[((kt * 4 + q) * 128 + dt * 16 + m) * 8];
            acc = __builtin_amdgcn_mfma_f32_16x16x32_bf16(wfrag, hfrag[kt], acc, 0, 0, 0);
        }
        // lane(m,q) holds Wh[node m][dt*16 + q*4 + r] -> packed 8B store
        if (nvalid) {
            unsigned int lo = ((unsigned int)f2bf(acc[1]) << 16) | f2bf(acc[0]);
            unsigned int hi = ((unsigned int)f2bf(acc[3]) << 16) | f2bf(acc[2]);
            uint2 pk; pk.x = lo; pk.y = hi;
            *(uint2*)(Whbf + (size_t)node * DIM + dt * 16 + q * 4) = pk;
        }
    }
}

// ---------------------------------------------------------------- edge logits -> exp -> packed record
// 2 edges/thread (grid 1250 blocks -> single residency round) for 2x
// memory-level parallelism on the random gather/atomic/store chains.
// ef.We dot computed cooperatively: 4-lane groups load full ef rows
// coalesced (1KB/wave/instr), shfl-reduce, stash 4 ed floats in tiny LDS
// (stride-5 pad -> <=2-way banks, free). 10.2 KB LDS -> 8 blocks/CU.
__global__ __launch_bounds__(256) void k_scatter(
    const int* __restrict__ ei,
    const float* __restrict__ ef,   // [E,16]
    const float* __restrict__ We,   // [4,16]
    const float* __restrict__ sc,   // [N,8]
    int* __restrict__ counts,
    uint4* __restrict__ brec)
{
    __shared__ float ed_s[512 * 5];   // [edge_local * 5 + head]
    int t = threadIdx.x;
    int eb = blockIdx.x * 512;

    // per-lane We chunk: lane's c = t&3 covers dims c*4..c*4+3 of each head row
    int c = t & 3;
    float4 w0 = *(const float4*)(We + 0 * 16 + c * 4);
    float4 w1 = *(const float4*)(We + 1 * 16 + c * 4);
    float4 w2 = *(const float4*)(We + 2 * 16 + c * 4);
    float4 w3 = *(const float4*)(We + 3 * 16 + c * 4);

    // phase 1: 8 passes x 64 edges; 4 lanes per edge, fully coalesced ef reads
#pragma unroll
    for (int p = 0; p < 8; ++p) {
        int el = p * 64 + (t >> 2);                 // local edge 0..511
        float4 f = *(const float4*)(ef + (size_t)(eb + el) * 16 + c * 4);
        float pd0 = f.x * w0.x + f.y * w0.y + f.z * w0.z + f.w * w0.w;
        float pd1 = f.x * w1.x + f.y * w1.y + f.z * w1.z + f.w * w1.w;
        float pd2 = f.x * w2.x + f.y * w2.y + f.z * w2.z + f.w * w2.w;
        float pd3 = f.x * w3.x + f.y * w3.y + f.z * w3.z + f.w * w3.w;
        pd0 += __shfl_xor(pd0, 1, 64); pd0 += __shfl_xor(pd0, 2, 64);
        pd1 += __shfl_xor(pd1, 1, 64); pd1 += __shfl_xor(pd1, 2, 64);
        pd2 += __shfl_xor(pd2, 1, 64); pd2 += __shfl_xor(pd2, 2, 64);
        pd3 += __shfl_xor(pd3, 1, 64); pd3 += __shfl_xor(pd3, 2, 64);
        // lane c stores head c of this edge
        float edv = c == 0 ? pd0 : (c == 1 ? pd1 : (c == 2 ? pd2 : pd3));
        ed_s[el * 5 + c] = edv;
    }

    // phase 2 prologue: issue BOTH edges' index loads / atomics / gathers
    // before any dependent math -> two independent chains in flight.
    int ea = eb + t, ebg = eb + t + 256;
    int srcA = ei[ea], dstA = ei[N_EDGES + ea];
    int srcB = ei[ebg], dstB = ei[N_EDGES + ebg];
    int slotA = atomicAdd(counts + dstA, 1);
    int slotB = atomicAdd(counts + dstB, 1);
    float4 ssA = *(const float4*)(sc + (size_t)srcA * 8);
    float4 sdA = *(const float4*)(sc + (size_t)dstA * 8 + 4);
    float4 ssB = *(const float4*)(sc + (size_t)srcB * 8);
    float4 sdB = *(const float4*)(sc + (size_t)dstB * 8 + 4);

    __syncthreads();

    float lgA[4] = {ssA.x + sdA.x, ssA.y + sdA.y, ssA.z + sdA.z, ssA.w + sdA.w};
    float lgB[4] = {ssB.x + sdB.x, ssB.y + sdB.y, ssB.z + sdB.z, ssB.w + sdB.w};
    const float* edA = ed_s + t * 5;
    const float* edB = ed_s + (t + 256) * 5;
#pragma unroll
    for (int hh = 0; hh < 4; ++hh) {
        float sA = lgA[hh];
        sA = sA > 0.f ? sA : 0.2f * sA;   // leaky_relu on node-score part only
        lgA[hh] = __expf(sA + edA[hh]);
        float sB = lgB[hh];
        sB = sB > 0.f ? sB : 0.2f * sB;
        lgB[hh] = __expf(sB + edB[hh]);
    }
    if (slotA < CAPB) {
        uint4 rec;
        rec.x = (unsigned int)srcA;
        rec.y = ((unsigned int)f2bf(lgA[1]) << 16) | f2bf(lgA[0]);
        rec.z = ((unsigned int)f2bf(lgA[3]) << 16) | f2bf(lgA[2]);
        rec.w = 0;
        brec[(size_t)dstA * CAPB + slotA] = rec;
    }
    if (slotB < CAPB) {
        uint4 rec;
        rec.x = (unsigned int)srcB;
        rec.y = ((unsigned int)f2bf(lgB[1]) << 16) | f2bf(lgB[0]);
        rec.z = ((unsigned int)f2bf(lgB[3]) << 16) | f2bf(lgB[2]);
        rec.w = 0;
        brec[(size_t)dstB * CAPB + slotB] = rec;
    }
}

// ---------------------------------------------------------------- fused agg + GELU + LN
// one wave per node; half-wave owns all 128 dims (4 dims/lane, 8B loads),
// two edges per j-step -> 8 cache lines in flight per load instruction.
__global__ __launch_bounds__(256) void k_node(
    const int* __restrict__ counts,
    const uint4* __restrict__ brec,
    const unsigned short* __restrict__ Whbf,
    const float* __restrict__ ln_scale, const float* __restrict__ ln_bias,
    float* __restrict__ out)
{
    __shared__ __align__(16) float p_s[4][CAPB * 4];
    __shared__ int s_s[4][CAPB];
    int w = threadIdx.x >> 6, l = threadIdx.x & 63;
    int n = blockIdx.x * 4 + w;                    // grid exact: 12500 blocks
    int deg = counts[n];
    deg = deg < CAPB ? deg : CAPB;
    size_t base = (size_t)n * CAPB;

    if (l < CAPB) {
        uint4 rec = make_uint4(0u, 0u, 0u, 0u);
        if (l < deg) rec = brec[base + l];
        float4 pv;
        pv.x = bfu2f_lo(rec.y); pv.y = bfu2f_hi(rec.y);
        pv.z = bfu2f_lo(rec.z); pv.w = bfu2f_hi(rec.z);
        *(float4*)&p_s[w][l * 4] = pv;             // zero-padded to CAPB
        s_s[w][l] = (int)rec.x;                    // pad src=0 (p=0 kills it)
    }
    __syncthreads();

    int li = l & 31, half = l >> 5;
    int hb = li >> 3;                              // head of dims li*4..+3
    float den = 0.f, b0 = 0.f, b1 = 0.f, b2 = 0.f, b3 = 0.f;
    int nch = (deg + 15) >> 4;                     // 16 edges per chunk (2/j-step)
    for (int c = 0; c < nch; ++c) {
        int e0 = c * 16 + half;
        float pv[8];
        uint2 uu[8];
#pragma unroll
        for (int j = 0; j < 8; ++j) {
            int e = e0 + j * 2;                    // e <= 47 < CAPB (zero-padded)
            int src = s_s[w][e];
            pv[j] = p_s[w][e * 4 + hb];
            uu[j] = *(const uint2*)(Whbf + (size_t)src * DIM + li * 4);
        }
#pragma unroll
        for (int j = 0; j < 8; ++j) {
            den += pv[j];
            b0 += pv[j] * bfu2f_lo(uu[j].x);
            b1 += pv[j] * bfu2f_hi(uu[j].x);
            b2 += pv[j] * bfu2f_lo(uu[j].y);
            b3 += pv[j] * bfu2f_hi(uu[j].y);
        }
    }
    // combine the two half-wave edge partitions (same dims in lanes l, l^32)
    den += __shfl_xor(den, 32, 64);
    b0 += __shfl_xor(b0, 32, 64);
    b1 += __shfl_xor(b1, 32, 64);
    b2 += __shfl_xor(b2, 32, 64);
    b3 += __shfl_xor(b3, 32, 64);

    float dd = den + 1e-9f;
    float x0 = b0 / dd, x1 = b1 / dd, x2 = b2 / dd, x3 = b3 / dd;
    const float k = 0.70710678118654752f;
    float g0 = 0.5f * x0 * (1.f + erff(x0 * k));
    float g1 = 0.5f * x1 * (1.f + erff(x1 * k));
    float g2 = 0.5f * x2 * (1.f + erff(x2 * k));
    float g3 = 0.5f * x3 * (1.f + erff(x3 * k));
    float s = g0 + g1 + g2 + g3;
    float ss = g0 * g0 + g1 * g1 + g2 * g2 + g3 * g3;
#pragma unroll
    for (int off = 1; off <= 16; off <<= 1) {      // reduce within 32-lane half
        s += __shfl_xor(s, off, 64);
        ss += __shfl_xor(ss, off, 64);
    }
    float mu = s * (1.f / 128.f);
    float var = ss * (1.f / 128.f) - mu * mu;
    float rstd = rsqrtf(var + 1e-5f);
    if (half == 0) {
        float4 sca = *(const float4*)(ln_scale + li * 4);
        float4 bi = *(const float4*)(ln_bias + li * 4);
        float4 o;
        o.x = (g0 - mu) * rstd * sca.x + bi.x;
        o.y = (g1 - mu) * rstd * sca.y + bi.y;
        o.z = (g2 - mu) * rstd * sca.z + bi.z;
        o.w = (g3 - mu) * rstd * sca.w + bi.w;
        *(float4*)(out + (size_t)n * DIM + li * 4) = o;
    }
}

extern "C" void kernel_launch(void* const* d_in, const int* in_sizes, int n_in,
                              void* d_out, int out_size, void* d_ws, size_t ws_size,
                              hipStream_t stream) {
    const float* h   = (const float*)d_in[0];
    const int*   ei  = (const int*)d_in[1];
    const float* ef  = (const float*)d_in[2];
    const float* W   = (const float*)d_in[3];
    const float* We  = (const float*)d_in[4];
    const float* a   = (const float*)d_in[5];
    const float* lsc = (const float*)d_in[6];
    const float* lbi = (const float*)d_in[7];

    char* ws = (char*)d_ws;
    size_t off = 0;
    unsigned short* Whbf = (unsigned short*)(ws + off); off += (size_t)N_NODES * DIM * 2;
    float* sc    = (float*)(ws + off); off += (size_t)N_NODES * 8 * 4;
    int*   counts= (int*)(ws + off);   off += (size_t)N_NODES * 4;
    uint4* brec  = (uint4*)(ws + off); off += (size_t)N_NODES * CAPB * 16;

    k_gemm<<<(N_NODES + 63) / 64, 256, 0, stream>>>(h, W, a, Whbf, sc, counts);
    k_scatter<<<N_EDGES / 512, 256, 0, stream>>>(ei, ef, We, sc, counts, brec);
    k_node<<<N_NODES / 4, 256, 0, stream>>>(counts, brec, Whbf, lsc, lbi,
                                            (float*)d_out);
}